// Round 4
// baseline (127.807 us; speedup 1.0000x reference)
//
#include <hip/hip_runtime.h>
#include <cstdint>

#define NV 200000
#define NCOLS 5
#define P 128
#define NE 8192
#define NC 1024

// Kernel 1: gather all clusters' coords once into dense float4 array.
// ws[c*P + p] = (data[v,1], data[v,2], data[v,3], 0) where v = clusts[c,p].
__global__ __launch_bounds__(256) void gather_kernel(
    const float* __restrict__ data,
    const int*   __restrict__ clusts,
    float4*      __restrict__ ws)
{
    const int idx = blockIdx.x * 256 + threadIdx.x;   // 0 .. NC*P-1
    const int v = clusts[idx];
    ws[idx] = make_float4(data[v * NCOLS + 1], data[v * NCOLS + 2],
                          data[v * NCOLS + 3], 0.f);
}

// Edge kernel: ONE WAVE PER EDGE (128-thread block = 2 waves = 2 edges).
// Round-3 lesson: single running-min = 256-link serial cmp/cndmask chain,
// VALUBusy 69%, latency-bound. Fix (round-0's trick at wave scope): EIGHT
// independent min-chains bd[m]/bk[m], one per register-resident b point.
// All chains are register-disjoint -> 8-way ILP on the update; instruction
// count per pair unchanged (cmp + 2 cndmask, k is an inline constant).
// Tie-break exactness: within chain m, j = tj+16m is fixed and k ascends,
// so flat = (ti+4k)*128 + j ascends; strict < keeps the first (smallest
// flat) min. Cross-chain and cross-lane combines use the packed
// (d2_bits << 32 | flat) u64 key => lexicographic (min d2, then min flat),
// bit-identical to jnp.argmin.
// No __syncthreads: each wave writes and reads only its own LDS half, so
// intra-wave lgkmcnt ordering (compiler-inserted) is sufficient; waves
// stay decoupled for latency hiding.
template <bool USE_WS>
__global__ __launch_bounds__(128) void clust_geo_edge_kernel(
    const float*  __restrict__ data,
    const int*    __restrict__ clusts,
    const int*    __restrict__ edge_index,
    const float4* __restrict__ ws,
    float*        __restrict__ out)
{
    const int w    = threadIdx.x >> 6;     // wave id within block: 0/1
    const int lane = threadIdx.x & 63;
    const int e    = blockIdx.x * 2 + w;   // one edge per wave

    __shared__ float4 x1s[2][P];
    __shared__ float4 x2s[2][P];

    const int c1 = edge_index[e];
    const int c2 = edge_index[NE + e];

    // Stage both clusters (4 float4 loads/lane, coalesced on the ws path).
    if (USE_WS) {
        x1s[w][lane]      = ws[c1 * P + lane];
        x1s[w][lane + 64] = ws[c1 * P + lane + 64];
        x2s[w][lane]      = ws[c2 * P + lane];
        x2s[w][lane + 64] = ws[c2 * P + lane + 64];
    } else {
        int v = clusts[c1 * P + lane];
        x1s[w][lane]      = make_float4(data[v * NCOLS + 1], data[v * NCOLS + 2],
                                        data[v * NCOLS + 3], 0.f);
        v = clusts[c1 * P + lane + 64];
        x1s[w][lane + 64] = make_float4(data[v * NCOLS + 1], data[v * NCOLS + 2],
                                        data[v * NCOLS + 3], 0.f);
        v = clusts[c2 * P + lane];
        x2s[w][lane]      = make_float4(data[v * NCOLS + 1], data[v * NCOLS + 2],
                                        data[v * NCOLS + 3], 0.f);
        v = clusts[c2 * P + lane + 64];
        x2s[w][lane + 64] = make_float4(data[v * NCOLS + 1], data[v * NCOLS + 2],
                                        data[v * NCOLS + 3], 0.f);
    }
    // (no barrier needed — per-wave-private LDS halves)

    // 4x16 lane grid: i = ti + 4*k (k=0..31, ascending), j = tj + 16*m (m=0..7).
    const int tj = lane & 15;
    const int ti = lane >> 4;

    // b tile resident as scalars (24 VGPR, no dead .w lane).
    float bx[8], by[8], bz[8];
    #pragma unroll
    for (int m = 0; m < 8; ++m) {
        const float4 v = x2s[w][tj + 16 * m];
        bx[m] = v.x; by[m] = v.y; bz[m] = v.z;
    }

    // Eight independent (value, k-index) min-chains.
    float bd[8];
    int   bk[8];
    #pragma unroll
    for (int m = 0; m < 8; ++m) { bd[m] = __builtin_inff(); bk[m] = 0; }

    // Exact replication of reference fp32 arithmetic: (dx*dx + dy*dy) + dz*dz,
    // no FMA contraction (argmin tie-breaking must match numpy).
    #pragma unroll
    for (int k = 0; k < 32; ++k) {
        const float4 av = x1s[w][ti + 4 * k];     // 16-lane broadcast read
        const float ax = av.x, ay = av.y, az = av.z;
        #pragma unroll
        for (int m = 0; m < 8; ++m) {
            const float dx = __fsub_rn(ax, bx[m]);
            const float dy = __fsub_rn(ay, by[m]);
            const float dz = __fsub_rn(az, bz[m]);
            const float d2 = __fadd_rn(__fadd_rn(__fmul_rn(dx, dx), __fmul_rn(dy, dy)),
                                       __fmul_rn(dz, dz));
            if (d2 < bd[m]) { bd[m] = d2; bk[m] = k; }   // k ascending per chain
        }
    }

    // Combine the 8 chains exactly via packed (d2, flat) keys.
    const int base = ti * P + tj;
    unsigned long long key = 0xffffffffffffffffull;
    #pragma unroll
    for (int m = 0; m < 8; ++m) {
        const unsigned flat = (unsigned)(base + (m << 4) + (bk[m] << 9)); // +512*k
        const unsigned long long km =
            ((unsigned long long)__float_as_uint(bd[m]) << 32) | flat;
        if (km < key) key = km;
    }

    // Wave-level (64-lane) min reduce — no cross-wave stage needed.
    for (int off = 32; off > 0; off >>= 1) {
        unsigned long long other = __shfl_down(key, off, 64);
        if (other < key) key = other;
    }

    if (lane == 0) {
        const int flat = (int)(key & 0xffffffffull);
        const int i1 = flat >> 7;
        const int i2 = flat & (P - 1);

        const float v1x = x1s[w][i1].x, v1y = x1s[w][i1].y, v1z = x1s[w][i1].z;
        const float v2x = x2s[w][i2].x, v2y = x2s[w][i2].y, v2z = x2s[w][i2].z;

        const float dx = v1x - v2x, dy = v1y - v2y, dz = v1z - v2z;
        const float lend = sqrtf(dx * dx + dy * dy + dz * dz);

        float nx, ny, nz;
        if (lend > 0.f) { nx = dx / lend; ny = dy / lend; nz = dz / lend; }
        else            { nx = dx;        ny = dy;        nz = dz;        }

        const float B[9] = { nx*nx, nx*ny, nx*nz,
                             ny*nx, ny*ny, ny*nz,
                             nz*nx, nz*ny, nz*nz };

        float* o = out + (size_t)e * 38;
        // feats: v1, v2, dispn, lend, B
        o[0] = v1x; o[1] = v1y; o[2] = v1z;
        o[3] = v2x; o[4] = v2y; o[5] = v2z;
        o[6] = nx;  o[7] = ny;  o[8] = nz;  o[9] = lend;
        #pragma unroll
        for (int q = 0; q < 9; ++q) o[10 + q] = B[q];
        // feats_flip: v2, v1, -dispn, lend, B
        o[19] = v2x; o[20] = v2y; o[21] = v2z;
        o[22] = v1x; o[23] = v1y; o[24] = v1z;
        o[25] = -nx; o[26] = -ny; o[27] = -nz; o[28] = lend;
        #pragma unroll
        for (int q = 0; q < 9; ++q) o[29 + q] = B[q];
    }
}

extern "C" void kernel_launch(void* const* d_in, const int* in_sizes, int n_in,
                              void* d_out, int out_size, void* d_ws, size_t ws_size,
                              hipStream_t stream) {
    const float* data       = (const float*)d_in[0];
    const int*   clusts     = (const int*)d_in[1];
    const int*   edge_index = (const int*)d_in[2];
    float*       out        = (float*)d_out;
    float4*      ws         = (float4*)d_ws;

    const size_t need = (size_t)NC * P * sizeof(float4);  // 2 MB
    if (ws_size >= need) {
        gather_kernel<<<(NC * P) / 256, 256, 0, stream>>>(data, clusts, ws);
        clust_geo_edge_kernel<true><<<NE / 2, 128, 0, stream>>>(data, clusts, edge_index, ws, out);
    } else {
        clust_geo_edge_kernel<false><<<NE / 2, 128, 0, stream>>>(data, clusts, edge_index, ws, out);
    }
}

// Round 5
// 93.230 us; speedup vs baseline: 1.3709x; 1.3709x over previous
//
#include <hip/hip_runtime.h>
#include <cstdint>

#define NV 200000
#define NCOLS 5
#define P 128
#define NE 8192
#define NC 1024

// Kernel 1: gather all clusters' coords once into dense float4 array.
// ws[c*P + p] = (data[v,1], data[v,2], data[v,3], 0) where v = clusts[c,p].
__global__ __launch_bounds__(256) void gather_kernel(
    const float* __restrict__ data,
    const int*   __restrict__ clusts,
    float4*      __restrict__ ws)
{
    const int idx = blockIdx.x * 256 + threadIdx.x;   // 0 .. NC*P-1
    const int v = clusts[idx];
    ws[idx] = make_float4(data[v * NCOLS + 1], data[v * NCOLS + 2],
                          data[v * NCOLS + 3], 0.f);
}

// Edge kernel: ONE WAVE PER EDGE (128-thread block = 2 waves = 2 edges).
//
// Round-3 lesson: single running-min = 256-link serial cmp/cndmask chain
// (VALUBusy 69%, latency-bound). Round-4 lesson: 8 chains + full 32-wide
// k-unroll let the scheduler hoist ALL 32 a-tile ds_reads -> 216 VGPR ->
// 2 waves/SIMD, occupancy 10% (worse). This version keeps the 8
// independent chains but bounds a-liveness with a ROLLED group loop
// (4 x 8): only 8 a-points (24 scalar VGPRs) live per group, and the
// loop-carried bd/bk arrays fence scheduler hoisting across groups.
// Target ~96 VGPR -> 4-5 waves/SIMD.
//
// Tie-break exactness: within chain m, j = tj+16m fixed, k ascends
// (kk outer asc, u inner asc) => flat = base+512k+16m ascends; strict <
// keeps the first (smallest-flat) min. Cross-chain (m asc) and cross-lane
// combines use the packed (d2_bits<<32 | flat) u64 key => lexicographic
// (min d2, then min flat), bit-identical to jnp.argmin.
//
// No __syncthreads: each wave writes and reads only its own LDS half;
// intra-wave LDS ordering via lgkmcnt is compiler-guaranteed.
template <bool USE_WS>
__global__ __launch_bounds__(128) void clust_geo_edge_kernel(
    const float*  __restrict__ data,
    const int*    __restrict__ clusts,
    const int*    __restrict__ edge_index,
    const float4* __restrict__ ws,
    float*        __restrict__ out)
{
    const int w    = threadIdx.x >> 6;     // wave id within block: 0/1
    const int lane = threadIdx.x & 63;
    const int e    = blockIdx.x * 2 + w;   // one edge per wave

    __shared__ float4 x1s[2][P];
    __shared__ float4 x2s[2][P];

    const int c1 = edge_index[e];
    const int c2 = edge_index[NE + e];

    // Stage both clusters (4 float4 loads/lane, coalesced on the ws path).
    if (USE_WS) {
        x1s[w][lane]      = ws[c1 * P + lane];
        x1s[w][lane + 64] = ws[c1 * P + lane + 64];
        x2s[w][lane]      = ws[c2 * P + lane];
        x2s[w][lane + 64] = ws[c2 * P + lane + 64];
    } else {
        int v = clusts[c1 * P + lane];
        x1s[w][lane]      = make_float4(data[v * NCOLS + 1], data[v * NCOLS + 2],
                                        data[v * NCOLS + 3], 0.f);
        v = clusts[c1 * P + lane + 64];
        x1s[w][lane + 64] = make_float4(data[v * NCOLS + 1], data[v * NCOLS + 2],
                                        data[v * NCOLS + 3], 0.f);
        v = clusts[c2 * P + lane];
        x2s[w][lane]      = make_float4(data[v * NCOLS + 1], data[v * NCOLS + 2],
                                        data[v * NCOLS + 3], 0.f);
        v = clusts[c2 * P + lane + 64];
        x2s[w][lane + 64] = make_float4(data[v * NCOLS + 1], data[v * NCOLS + 2],
                                        data[v * NCOLS + 3], 0.f);
    }
    // (no barrier needed — per-wave-private LDS halves)

    // 4x16 lane grid: i = ti + 4*k (k=0..31), j = tj + 16*m (m=0..7).
    const int tj = lane & 15;
    const int ti = lane >> 4;

    // b tile resident as scalars (24 VGPR, no dead .w lane).
    float bx[8], by[8], bz[8];
    #pragma unroll
    for (int m = 0; m < 8; ++m) {
        const float4 v = x2s[w][tj + 16 * m];
        bx[m] = v.x; by[m] = v.y; bz[m] = v.z;
    }

    // Eight independent (value, k-index) min-chains.
    float bd[8];
    int   bk[8];
    #pragma unroll
    for (int m = 0; m < 8; ++m) { bd[m] = __builtin_inff(); bk[m] = 0; }

    // Exact replication of reference fp32 arithmetic: (dx*dx + dy*dy) + dz*dz,
    // no FMA contraction (argmin tie-breaking must match numpy).
    #pragma unroll 1
    for (int kk = 0; kk < 4; ++kk) {
        // 8 broadcast a-loads for this group (24 live scalar VGPRs).
        float ax[8], ay[8], az[8];
        #pragma unroll
        for (int u = 0; u < 8; ++u) {
            const float4 av = x1s[w][ti + 4 * (kk * 8 + u)];
            ax[u] = av.x; ay[u] = av.y; az[u] = av.z;
        }
        #pragma unroll
        for (int u = 0; u < 8; ++u) {
            #pragma unroll
            for (int m = 0; m < 8; ++m) {
                const float dx = __fsub_rn(ax[u], bx[m]);
                const float dy = __fsub_rn(ay[u], by[m]);
                const float dz = __fsub_rn(az[u], bz[m]);
                const float d2 = __fadd_rn(__fadd_rn(__fmul_rn(dx, dx), __fmul_rn(dy, dy)),
                                           __fmul_rn(dz, dz));
                if (d2 < bd[m]) { bd[m] = d2; bk[m] = kk * 8 + u; }  // k ascending
            }
        }
    }

    // Combine the 8 chains exactly via packed (d2, flat) keys.
    const int base = ti * P + tj;
    unsigned long long key = 0xffffffffffffffffull;
    #pragma unroll
    for (int m = 0; m < 8; ++m) {
        const unsigned flat = (unsigned)(base + (m << 4) + (bk[m] << 9)); // +512*k
        const unsigned long long km =
            ((unsigned long long)__float_as_uint(bd[m]) << 32) | flat;
        if (km < key) key = km;
    }

    // Wave-level (64-lane) min reduce — no cross-wave stage needed.
    for (int off = 32; off > 0; off >>= 1) {
        unsigned long long other = __shfl_down(key, off, 64);
        if (other < key) key = other;
    }

    if (lane == 0) {
        const int flat = (int)(key & 0xffffffffull);
        const int i1 = flat >> 7;
        const int i2 = flat & (P - 1);

        const float v1x = x1s[w][i1].x, v1y = x1s[w][i1].y, v1z = x1s[w][i1].z;
        const float v2x = x2s[w][i2].x, v2y = x2s[w][i2].y, v2z = x2s[w][i2].z;

        const float dx = v1x - v2x, dy = v1y - v2y, dz = v1z - v2z;
        const float lend = sqrtf(dx * dx + dy * dy + dz * dz);

        float nx, ny, nz;
        if (lend > 0.f) { nx = dx / lend; ny = dy / lend; nz = dz / lend; }
        else            { nx = dx;        ny = dy;        nz = dz;        }

        const float B[9] = { nx*nx, nx*ny, nx*nz,
                             ny*nx, ny*ny, ny*nz,
                             nz*nx, nz*ny, nz*nz };

        float* o = out + (size_t)e * 38;
        // feats: v1, v2, dispn, lend, B
        o[0] = v1x; o[1] = v1y; o[2] = v1z;
        o[3] = v2x; o[4] = v2y; o[5] = v2z;
        o[6] = nx;  o[7] = ny;  o[8] = nz;  o[9] = lend;
        #pragma unroll
        for (int q = 0; q < 9; ++q) o[10 + q] = B[q];
        // feats_flip: v2, v1, -dispn, lend, B
        o[19] = v2x; o[20] = v2y; o[21] = v2z;
        o[22] = v1x; o[23] = v1y; o[24] = v1z;
        o[25] = -nx; o[26] = -ny; o[27] = -nz; o[28] = lend;
        #pragma unroll
        for (int q = 0; q < 9; ++q) o[29 + q] = B[q];
    }
}

extern "C" void kernel_launch(void* const* d_in, const int* in_sizes, int n_in,
                              void* d_out, int out_size, void* d_ws, size_t ws_size,
                              hipStream_t stream) {
    const float* data       = (const float*)d_in[0];
    const int*   clusts     = (const int*)d_in[1];
    const int*   edge_index = (const int*)d_in[2];
    float*       out        = (float*)d_out;
    float4*      ws         = (float4*)d_ws;

    const size_t need = (size_t)NC * P * sizeof(float4);  // 2 MB
    if (ws_size >= need) {
        gather_kernel<<<(NC * P) / 256, 256, 0, stream>>>(data, clusts, ws);
        clust_geo_edge_kernel<true><<<NE / 2, 128, 0, stream>>>(data, clusts, edge_index, ws, out);
    } else {
        clust_geo_edge_kernel<false><<<NE / 2, 128, 0, stream>>>(data, clusts, edge_index, ws, out);
    }
}